// Round 6
// baseline (114.121 us; speedup 1.0000x reference)
//
#include <hip/hip_runtime.h>
#include <math.h>

#define BATCH 64
#define T 4096
#define ALPH 32
#define NS 128
#define MB 16              // batches per wave (MFMA M)
#define NGRP 4             // BATCH/MB
#define NCHUNK 256
#define CL 16              // T/NCHUNK
#define WARM 16

typedef __bf16 bf16x8 __attribute__((ext_vector_type(8)));
typedef short  short8 __attribute__((ext_vector_type(8)));
typedef float  f32x4  __attribute__((ext_vector_type(4)));

// ws layout (float offsets):
//   frag : ushort, 32 frags * 1024 B = 32 KB   at 0      (B-operand fragments of A, MFMA lane layout)
//   Bme  : ushort[32][128] e-major bf16 (8 KB) at 8192   (Bme[tk][c*8+nt] = Bm[tk][nt*16+c])
//   I    : float[128], permuted storage order  at 10240
//   part : float[NCHUNK][64]                   at 10368
//   tok  : uchar[BATCH*T]                      at 26752
#define WS_FRAG 0
#define WS_BME  8192
#define WS_I    10240
#define WS_PART 10368
#define WS_TOK_F 26752

static __device__ inline unsigned short f2u(float f) {
    __bf16 b = (__bf16)f;
    return __builtin_bit_cast(unsigned short, b);
}

// Storage permutation for alpha (and I): storage slot p holds logical state
//   n(p) = ( (p>>5)*2 + (p&1) )*16 + ((p>>1)&15)
// so that C/D writes pack as dword pairs (nt even/odd adjacent) and A-operand
// reads are contiguous b128 at [m][kc*32 + quad*8].

// ---------------- setup ----------------
// blocks [0,1024): token extraction; [1024,1152): A-row softmax + frag pack;
// block 1152: Bm column softmax (e-major bf16) + I softmax (permuted).
__global__ __launch_bounds__(256) void setup_kernel(const float* __restrict__ onehot,
                                                    const float* __restrict__ A_logits,
                                                    const float* __restrict__ B_logits,
                                                    const float* __restrict__ I_logits,
                                                    float* __restrict__ ws,
                                                    unsigned char* __restrict__ tok) {
    unsigned short* frag = (unsigned short*)(ws + WS_FRAG);
    unsigned short* Bme  = (unsigned short*)(ws + WS_BME);
    float* I_ws = ws + WS_I;
    const int blk = blockIdx.x;
    const int tid = threadIdx.x;

    if (blk < 1024) {
        int b = blk >> 4;
        int t = (blk & 15) * 256 + tid;
        const float4* p = (const float4*)(onehot + ((size_t)b * T + t) * ALPH);
        int tk = 0;
        #pragma unroll
        for (int q = 0; q < 8; ++q) {
            float4 v = p[q];
            if (v.x > 0.5f) tk = 4 * q + 0;
            if (v.y > 0.5f) tk = 4 * q + 1;
            if (v.z > 0.5f) tk = 4 * q + 2;
            if (v.w > 0.5f) tk = 4 * q + 3;
        }
        tok[(size_t)b * T + t] = (unsigned char)tk;
        return;
    }

    if (blk == 1024 + NS) {
        // Bm column softmax -> Bme bf16 e-major
        if (tid < NS) {
            int s = tid;
            float m = -1e30f;
            for (int a = 0; a < ALPH; ++a) m = fmaxf(m, B_logits[a * NS + s]);
            float sum = 0.f;
            for (int a = 0; a < ALPH; ++a) sum += expf(B_logits[a * NS + s] - m);
            float inv = 1.0f / sum;
            int idx = (s & 15) * 8 + (s >> 4);  // c*8 + nt
            for (int a = 0; a < ALPH; ++a)
                Bme[a * NS + idx] = f2u(expf(B_logits[a * NS + s] - m) * inv);
        }
        // I softmax (all 256 threads participate in reduction)
        __shared__ float redm[4];
        __shared__ float reds[4];
        float x = (tid < NS) ? I_logits[tid] : -1e30f;
        float m = x;
        #pragma unroll
        for (int off = 1; off < 64; off <<= 1) m = fmaxf(m, __shfl_xor(m, off));
        int wid = tid >> 6;
        if ((tid & 63) == 0) redm[wid] = m;
        __syncthreads();
        m = fmaxf(fmaxf(redm[0], redm[1]), fmaxf(redm[2], redm[3]));
        float e = (tid < NS) ? expf(x - m) : 0.0f;
        float sg = e;
        #pragma unroll
        for (int off = 1; off < 64; off <<= 1) sg += __shfl_xor(sg, off);
        if ((tid & 63) == 0) reds[wid] = sg;
        __syncthreads();
        float total = (reds[0] + reds[1]) + (reds[2] + reds[3]);
        if (tid < NS) {
            int n = tid;
            int p = (n >> 5) * 32 + (n & 15) * 2 + ((n >> 4) & 1);  // inverse perm
            I_ws[p] = e / total;
        }
        return;
    }

    // A-row softmax, row rho, then scatter into MFMA fragment layout
    int rho = blk - 1024;
    __shared__ float redm[4];
    __shared__ float reds[4];
    float x = (tid < NS) ? A_logits[rho * NS + tid] : -1e30f;
    float m = x;
    #pragma unroll
    for (int off = 1; off < 64; off <<= 1) m = fmaxf(m, __shfl_xor(m, off));
    int wid = tid >> 6;
    if ((tid & 63) == 0) redm[wid] = m;
    __syncthreads();
    m = fmaxf(fmaxf(redm[0], redm[1]), fmaxf(redm[2], redm[3]));
    float e = (tid < NS) ? expf(x - m) : 0.0f;
    float sg = e;
    #pragma unroll
    for (int off = 1; off < 64; off <<= 1) sg += __shfl_xor(sg, off);
    if ((tid & 63) == 0) reds[wid] = sg;
    __syncthreads();
    float total = (reds[0] + reds[1]) + (reds[2] + reds[3]);
    if (tid < NS) {
        float v = e / total;
        int gamma = tid;                       // A column
        int kc   = rho >> 5;
        int jlow = (rho >> 4) & 1;
        int quad = (rho >> 2) & 3;
        int j    = (rho & 3) * 2 + jlow;
        int nt   = gamma >> 4;
        int col  = gamma & 15;
        int lane = quad * 16 + col;
        int fid  = kc * 8 + nt;
        frag[fid * 512 + lane * 8 + j] = f2u(v);
    }
}

// ---------------- hmm ----------------
// Block bx = chunk c; its 4 waves handle batch groups g=0..3 fully
// independently (no barriers in the chain). Per step, a wave computes
// new_alpha[16x128] = (alpha . A) * E via 32 MFMAs; alpha round-trips LDS
// in permuted storage order. Ledger: old-sum semantics; chunk c owns global
// steps t = c*CL .. c*CL+CL-1; warmup mass discarded at j=WARM.
__global__ __launch_bounds__(256, 1) void hmm_kernel(const float* __restrict__ ws,
                                                     const unsigned char* __restrict__ tok_g,
                                                     float* __restrict__ part) {
    const unsigned short* Bme_g = (const unsigned short*)(ws + WS_BME);
    const float* I_ws = ws + WS_I;
    const char* frag_g = (const char*)(ws + WS_FRAG);

    const int c    = blockIdx.x;
    const int tid  = threadIdx.x;
    const int g    = tid >> 6;       // wave = batch group
    const int lane = tid & 63;
    const int quad = lane >> 4;
    const int col  = lane & 15;

    __shared__ unsigned short Bme_lds[ALPH * NS];                 // 8 KB
    __shared__ __align__(16) short alpha_lds[NGRP][2][MB * 136];  // bf16, stride 136 shorts
    __shared__ unsigned char tok_lds[(CL + WARM) * BATCH];        // [t][b], 2 KB

    const int t0     = (c == 0) ? 0 : (c * CL - WARM);
    const int nsteps = (c == 0) ? (CL - 1) : (CL + WARM - 1);
    const int ntok   = nsteps + 1;
    const int resetj = (c == 0) ? -1 : WARM;

    // stage Bme (coalesced dwords)
    {
        const unsigned* src = (const unsigned*)Bme_g;
        unsigned* dst = (unsigned*)Bme_lds;
        #pragma unroll
        for (int i = 0; i < 8; ++i) dst[i * 256 + tid] = src[i * 256 + tid];
    }
    // stage tokens [t][b]: thread (b = tid&63, half = tid>>6) loads 8 tokens
    {
        int b = tid & 63, half = tid >> 6;
        if (half * 8 < ntok) {
            uint2 v = *(const uint2*)(tok_g + (size_t)b * T + t0 + half * 8);
            unsigned lo = v.x, hi = v.y;
            #pragma unroll
            for (int i = 0; i < 4; ++i) {
                tok_lds[(half * 8 + i) * 64 + b]     = (unsigned char)((lo >> (8 * i)) & 255);
                tok_lds[(half * 8 + 4 + i) * 64 + b] = (unsigned char)((hi >> (8 * i)) & 255);
            }
        }
    }
    // load B-fragments (coalesced 16B, L2-broadcast across blocks)
    bf16x8 bfr[32];
    #pragma unroll
    for (int fid = 0; fid < 32; ++fid)
        bfr[fid] = __builtin_bit_cast(bf16x8, *(const short8*)(frag_g + fid * 1024 + lane * 16));

    __syncthreads();

    // initial alpha in storage order: chunk 0 exact (I*E0), else uniform
    {
        #pragma unroll
        for (int it = 0; it < 32; ++it) {
            int idx = it * 64 + lane;
            int m = idx >> 7, p = idx & 127;
            float val;
            if (c == 0) {
                int tk0 = tok_lds[0 * 64 + g * 16 + m];
                int nt = ((p >> 5) << 1) + (p & 1);
                int cc = (p >> 1) & 15;
                float bm = (float)__builtin_bit_cast(__bf16, Bme_lds[tk0 * NS + cc * 8 + nt]);
                val = I_ws[p] * bm;
            } else {
                val = 1.0f;
            }
            alpha_lds[g][0][m * 136 + p] = (short)f2u(val);
        }
    }

    float loglik = 0.0f;  // ledger for batch m=col (uniform across quads)

    for (int j = 1; j <= nsteps; ++j) {
        const int rb = (j + 1) & 1;
        const int wb = j & 1;
        const bool do_norm = ((j & 7) == 0);

        // tokens + emissions (independent of alpha)
        unsigned tokp = *(const unsigned*)&tok_lds[j * 64 + g * 16 + quad * 4];
        bf16x8 efr[4];
        #pragma unroll
        for (int r = 0; r < 4; ++r) {
            int tk = (tokp >> (8 * r)) & 255;
            efr[r] = *(const bf16x8*)&Bme_lds[tk * NS + col * 8];
        }

        // A-operand fragments
        const short* ap = &alpha_lds[g][rb][col * 136 + quad * 8];
        bf16x8 afr[4];
        #pragma unroll
        for (int kc = 0; kc < 4; ++kc)
            afr[kc] = *(const bf16x8*)(ap + kc * 32);

        f32x4 acc[8];
        #pragma unroll
        for (int nt = 0; nt < 8; ++nt) acc[nt] = (f32x4){0.f, 0.f, 0.f, 0.f};
        #pragma unroll
        for (int nt = 0; nt < 8; ++nt) {
            #pragma unroll
            for (int kc = 0; kc < 4; ++kc)
                acc[nt] = __builtin_amdgcn_mfma_f32_16x16x32_bf16(afr[kc], bfr[kc * 8 + nt], acc[nt], 0, 0, 0);
        }

        float inv[4] = {1.0f, 1.0f, 1.0f, 1.0f};
        if (do_norm) {
            float asum = 0.f;
            #pragma unroll
            for (int kc = 0; kc < 4; ++kc) {
                #pragma unroll
                for (int jj = 0; jj < 8; ++jj) asum += (float)afr[kc][jj];
            }
            asum += __shfl_xor(asum, 16);
            asum += __shfl_xor(asum, 32);           // asum = mass of batch m=col
            float lg = __logf(asum);
            loglik = (j == resetj) ? 0.0f : (loglik + lg);
            #pragma unroll
            for (int r = 0; r < 4; ++r)
                inv[r] = __builtin_amdgcn_rcpf(__shfl(asum, quad * 4 + r));  // scale for row m=quad*4+r
        }

        // emission multiply + pack + packed writes (storage order)
        #pragma unroll
        for (int r = 0; r < 4; ++r) {
            unsigned* wrow = (unsigned*)&alpha_lds[g][wb][(quad * 4 + r) * 136];
            #pragma unroll
            for (int a = 0; a < 4; ++a) {
                float x0 = acc[2 * a][r]     * (float)efr[r][2 * a]     * inv[r];
                float x1 = acc[2 * a + 1][r] * (float)efr[r][2 * a + 1] * inv[r];
                wrow[a * 16 + col] = (unsigned)f2u(x0) | ((unsigned)f2u(x1) << 16);
            }
        }
    }

    // final flush: loglik[m] += log(sum_p alpha_final[m][p])
    {
        const short* ap = &alpha_lds[g][nsteps & 1][col * 136 + quad * 8];
        float tot = 0.f;
        #pragma unroll
        for (int kc = 0; kc < 4; ++kc) {
            bf16x8 av = *(const bf16x8*)(ap + kc * 32);
            #pragma unroll
            for (int jj = 0; jj < 8; ++jj) tot += (float)av[jj];
        }
        tot += __shfl_xor(tot, 16);
        tot += __shfl_xor(tot, 32);
        if (quad == 0)
            part[c * 64 + g * 16 + col] = loglik + __logf(tot);
    }
}

// ---------------- reduce ----------------
__global__ __launch_bounds__(256) void reduce_kernel(const float* __restrict__ part,
                                                     float* __restrict__ out) {
    __shared__ float red[4][64];
    int b = threadIdx.x & 63;
    int cg = threadIdx.x >> 6;
    float s = 0.f;
    #pragma unroll 4
    for (int k = 0; k < 64; ++k)
        s += part[(cg * 64 + k) * 64 + b];
    red[cg][b] = s;
    __syncthreads();
    if (threadIdx.x < 64)
        out[threadIdx.x] = (red[0][threadIdx.x] + red[1][threadIdx.x]) +
                           (red[2][threadIdx.x] + red[3][threadIdx.x]);
}

extern "C" void kernel_launch(void* const* d_in, const int* in_sizes, int n_in,
                              void* d_out, int out_size, void* d_ws, size_t ws_size,
                              hipStream_t stream) {
    const float* onehot   = (const float*)d_in[0];
    const float* A_logits = (const float*)d_in[1];
    const float* B_logits = (const float*)d_in[2];
    const float* I_logits = (const float*)d_in[3];
    float* ws  = (float*)d_ws;
    float* out = (float*)d_out;
    unsigned char* tok = (unsigned char*)(ws + WS_TOK_F);

    setup_kernel<<<dim3(1024 + NS + 1), dim3(256), 0, stream>>>(
        onehot, A_logits, B_logits, I_logits, ws, tok);
    hmm_kernel<<<dim3(NCHUNK), dim3(256), 0, stream>>>(ws, tok, ws + WS_PART);
    reduce_kernel<<<dim3(1), dim3(256), 0, stream>>>(ws + WS_PART, out);
}

// Round 8
// 112.866 us; speedup vs baseline: 1.0111x; 1.0111x over previous
//
#include <hip/hip_runtime.h>
#include <math.h>

#define BATCH 64
#define T 4096
#define ALPH 32
#define NS 128
#define MB 16              // batches per wave (MFMA M)
#define NGRP 4             // BATCH/MB
#define NCHUNK 512
#define CL 8               // T/NCHUNK
#define WARM 16

typedef __bf16 bf16x8 __attribute__((ext_vector_type(8)));
typedef short  short8 __attribute__((ext_vector_type(8)));
typedef float  f32x4  __attribute__((ext_vector_type(4)));

// ws layout (float offsets):
//   frag : ushort, 32 frags * 1024 B = 32 KB   at 0      (B-operand fragments of A)
//   Bme  : ushort[32][128] e-major bf16 (8 KB) at 8192   (Bme[tk][c*8+nt] = Bm[tk][nt*16+c])
//   I    : float[128], permuted storage order  at 10240
//   tok  : uchar[BATCH*T]                      at 10368
#define WS_FRAG 0
#define WS_BME  8192
#define WS_I    10240
#define WS_TOK_F 10368

static __device__ inline unsigned short f2u(float f) {
    __bf16 b = (__bf16)f;
    return __builtin_bit_cast(unsigned short, b);
}

// Storage permutation for alpha/I: storage slot p holds logical state
//   n(p) = ((p>>5)*2 + (p&1))*16 + ((p>>1)&15)
// C/D writes pack as dword pairs; A-operand reads are contiguous b128.

// ---------------- setup ----------------
// blocks [0,1024): token extraction; [1024,1152): A-row softmax + frag pack;
// block 1152: Bm column softmax (e-major bf16) + I softmax + zero d_out.
__global__ __launch_bounds__(256) void setup_kernel(const float* __restrict__ onehot,
                                                    const float* __restrict__ A_logits,
                                                    const float* __restrict__ B_logits,
                                                    const float* __restrict__ I_logits,
                                                    float* __restrict__ ws,
                                                    float* __restrict__ out,
                                                    unsigned char* __restrict__ tok) {
    unsigned short* frag = (unsigned short*)(ws + WS_FRAG);
    unsigned short* Bme  = (unsigned short*)(ws + WS_BME);
    float* I_ws = ws + WS_I;
    const int blk = blockIdx.x;
    const int tid = threadIdx.x;

    if (blk < 1024) {
        int b = blk >> 4;
        int t = (blk & 15) * 256 + tid;
        const float4* p = (const float4*)(onehot + ((size_t)b * T + t) * ALPH);
        int tk = 0;
        #pragma unroll
        for (int q = 0; q < 8; ++q) {
            float4 v = p[q];
            if (v.x > 0.5f) tk = 4 * q + 0;
            if (v.y > 0.5f) tk = 4 * q + 1;
            if (v.z > 0.5f) tk = 4 * q + 2;
            if (v.w > 0.5f) tk = 4 * q + 3;
        }
        tok[(size_t)b * T + t] = (unsigned char)tk;
        return;
    }

    if (blk == 1024 + NS) {
        // Bm column softmax -> Bme bf16 e-major; zero out[]
        if (tid < NS) {
            int s = tid;
            float m = -1e30f;
            for (int a = 0; a < ALPH; ++a) m = fmaxf(m, B_logits[a * NS + s]);
            float sum = 0.f;
            for (int a = 0; a < ALPH; ++a) sum += expf(B_logits[a * NS + s] - m);
            float inv = 1.0f / sum;
            int idx = (s & 15) * 8 + (s >> 4);  // c*8 + nt
            for (int a = 0; a < ALPH; ++a)
                Bme[a * NS + idx] = f2u(expf(B_logits[a * NS + s] - m) * inv);
        } else if (tid < NS + BATCH) {
            out[tid - NS] = 0.0f;
        }
        // I softmax
        __shared__ float redm[4];
        __shared__ float reds[4];
        float x = (tid < NS) ? I_logits[tid] : -1e30f;
        float m = x;
        #pragma unroll
        for (int off = 1; off < 64; off <<= 1) m = fmaxf(m, __shfl_xor(m, off));
        int wid = tid >> 6;
        if ((tid & 63) == 0) redm[wid] = m;
        __syncthreads();
        m = fmaxf(fmaxf(redm[0], redm[1]), fmaxf(redm[2], redm[3]));
        float e = (tid < NS) ? expf(x - m) : 0.0f;
        float sg = e;
        #pragma unroll
        for (int off = 1; off < 64; off <<= 1) sg += __shfl_xor(sg, off);
        if ((tid & 63) == 0) reds[wid] = sg;
        __syncthreads();
        float total = (reds[0] + reds[1]) + (reds[2] + reds[3]);
        if (tid < NS) {
            int n = tid;
            int p = (n >> 5) * 32 + (n & 15) * 2 + ((n >> 4) & 1);  // inverse perm
            I_ws[p] = e / total;
        }
        return;
    }

    // A-row softmax, row rho, scattered into MFMA B-fragment layout
    int rho = blk - 1024;
    __shared__ float redm[4];
    __shared__ float reds[4];
    float x = (tid < NS) ? A_logits[rho * NS + tid] : -1e30f;
    float m = x;
    #pragma unroll
    for (int off = 1; off < 64; off <<= 1) m = fmaxf(m, __shfl_xor(m, off));
    int wid = tid >> 6;
    if ((tid & 63) == 0) redm[wid] = m;
    __syncthreads();
    m = fmaxf(fmaxf(redm[0], redm[1]), fmaxf(redm[2], redm[3]));
    float e = (tid < NS) ? expf(x - m) : 0.0f;
    float sg = e;
    #pragma unroll
    for (int off = 1; off < 64; off <<= 1) sg += __shfl_xor(sg, off);
    if ((tid & 63) == 0) reds[wid] = sg;
    __syncthreads();
    float total = (reds[0] + reds[1]) + (reds[2] + reds[3]);
    if (tid < NS) {
        float v = e / total;
        int gamma = tid;
        int kc   = rho >> 5;
        int jlow = (rho >> 4) & 1;
        int quad = (rho >> 2) & 3;
        int j    = (rho & 3) * 2 + jlow;
        int nt   = gamma >> 4;
        int col  = gamma & 15;
        int lane = quad * 16 + col;
        int fid  = kc * 8 + nt;
        frag[fid * 512 + lane * 8 + j] = f2u(v);
    }
}

// ---------------- hmm ----------------
// Block = chunk c; 4 independent waves (one per batch group), no barriers in
// the chain. Alpha updated IN PLACE (wave program order: all fragment reads
// precede the writes). t0 clamped at 0: chunks whose warmup window would
// start before t=0 (c=0,1) instead start EXACTLY from I*E0 and discard the
// ledger at resetj = c*CL - t0, so every global step is counted exactly once.
__global__ __launch_bounds__(256, 2) void hmm_kernel(const float* __restrict__ ws,
                                                     const unsigned char* __restrict__ tok_g,
                                                     float* __restrict__ out) {
    const unsigned short* Bme_g = (const unsigned short*)(ws + WS_BME);
    const float* I_ws = ws + WS_I;
    const char* frag_g = (const char*)(ws + WS_FRAG);

    const int c    = blockIdx.x;
    const int tid  = threadIdx.x;
    const int g    = tid >> 6;
    const int lane = tid & 63;
    const int quad = lane >> 4;
    const int col  = lane & 15;

    __shared__ unsigned short Bme_lds[ALPH * NS];            // 8 KB
    __shared__ __align__(16) short alpha_lds[NGRP][MB * 136];
    __shared__ unsigned char tok_lds[(CL + WARM) * BATCH];   // [t][b]

    const int t0u    = c * CL - WARM;
    const int t0     = (t0u < 0) ? 0 : t0u;       // clamp: no negative reads
    const bool exact = (t0 == 0);                 // exact init from I*E0
    const int nsteps = (c + 1) * CL - 1 - t0;     // last local step -> global (c+1)*CL-1
    const int ntok   = nsteps + 1;
    const int resetj = c * CL - t0;               // 0 for c==0 (never fires; j>=1)

    // stage Bme
    {
        const unsigned* src = (const unsigned*)Bme_g;
        unsigned* dst = (unsigned*)Bme_lds;
        #pragma unroll
        for (int i = 0; i < 8; ++i) dst[i * 256 + tid] = src[i * 256 + tid];
    }
    // stage tokens [t][b]
    {
        int b = tid & 63, half = tid >> 6;
        if (half * 8 < ntok) {
            uint2 v = *(const uint2*)(tok_g + (size_t)b * T + t0 + half * 8);
            unsigned lo = v.x, hi = v.y;
            #pragma unroll
            for (int i = 0; i < 4; ++i) {
                tok_lds[(half * 8 + i) * 64 + b]     = (unsigned char)((lo >> (8 * i)) & 255);
                tok_lds[(half * 8 + 4 + i) * 64 + b] = (unsigned char)((hi >> (8 * i)) & 255);
            }
        }
    }
    // B-fragments (coalesced 16B, L2-broadcast)
    bf16x8 bfr[32];
    #pragma unroll
    for (int fid = 0; fid < 32; ++fid)
        bfr[fid] = __builtin_bit_cast(bf16x8, *(const short8*)(frag_g + fid * 1024 + lane * 16));

    __syncthreads();

    // initial alpha in storage order: exact chunks I*E0, else uniform
    {
        #pragma unroll
        for (int it = 0; it < 32; ++it) {
            int idx = it * 64 + lane;
            int m = idx >> 7, p = idx & 127;
            float val;
            if (exact) {
                int tk0 = tok_lds[0 * 64 + g * 16 + m];
                int nt = ((p >> 5) << 1) + (p & 1);
                int cc = (p >> 1) & 15;
                float bm = (float)__builtin_bit_cast(__bf16, Bme_lds[tk0 * NS + cc * 8 + nt]);
                val = I_ws[p] * bm;
            } else {
                val = 1.0f;
            }
            alpha_lds[g][m * 136 + p] = (short)f2u(val);
        }
    }

    float loglik = 0.0f;  // ledger for batch m=col (uniform across quads)

    for (int j = 1; j <= nsteps; ++j) {
        const bool do_norm = ((j & 7) == 0) || (j == resetj);

        // tokens + emissions (independent of alpha)
        unsigned tokp = *(const unsigned*)&tok_lds[j * 64 + g * 16 + quad * 4];
        bf16x8 efr[4];
        #pragma unroll
        for (int r = 0; r < 4; ++r) {
            int tk = (tokp >> (8 * r)) & 255;
            efr[r] = *(const bf16x8*)&Bme_lds[tk * NS + col * 8];
        }

        // A-operand fragments
        const short* ap = &alpha_lds[g][col * 136 + quad * 8];
        bf16x8 afr[4];
        #pragma unroll
        for (int kc = 0; kc < 4; ++kc)
            afr[kc] = *(const bf16x8*)(ap + kc * 32);

        f32x4 acc[8];
        #pragma unroll
        for (int nt = 0; nt < 8; ++nt) acc[nt] = (f32x4){0.f, 0.f, 0.f, 0.f};
        #pragma unroll
        for (int nt = 0; nt < 8; ++nt) {
            #pragma unroll
            for (int kc = 0; kc < 4; ++kc)
                acc[nt] = __builtin_amdgcn_mfma_f32_16x16x32_bf16(afr[kc], bfr[kc * 8 + nt], acc[nt], 0, 0, 0);
        }

        float vv[4][8];
        #pragma unroll
        for (int r = 0; r < 4; ++r) {
            #pragma unroll
            for (int i = 0; i < 8; ++i)
                vv[r][i] = acc[i][r] * (float)efr[r][i];
        }

        if (do_norm) {
            float asum = 0.f;
            #pragma unroll
            for (int kc = 0; kc < 4; ++kc) {
                #pragma unroll
                for (int jj = 0; jj < 8; ++jj) asum += (float)afr[kc][jj];
            }
            asum += __shfl_xor(asum, 16);
            asum += __shfl_xor(asum, 32);           // mass of batch m=col
            float lg = __logf(asum);
            loglik = (j == resetj) ? 0.0f : (loglik + lg);
            #pragma unroll
            for (int r = 0; r < 4; ++r) {
                float iv = __builtin_amdgcn_rcpf(__shfl(asum, quad * 4 + r));
                #pragma unroll
                for (int i = 0; i < 8; ++i) vv[r][i] *= iv;
            }
        }

        // pack (round-half-up bf16, alpha>0) + write, storage order
        #pragma unroll
        for (int r = 0; r < 4; ++r) {
            unsigned* wrow = (unsigned*)&alpha_lds[g][(quad * 4 + r) * 136];
            #pragma unroll
            for (int a = 0; a < 4; ++a) {
                unsigned u0 = __builtin_bit_cast(unsigned, vv[r][2 * a])     + 0x8000u;
                unsigned u1 = __builtin_bit_cast(unsigned, vv[r][2 * a + 1]) + 0x8000u;
                wrow[a * 16 + col] = __builtin_amdgcn_perm(u1, u0, 0x07060302u);
            }
        }
    }

    // final flush: out[m] += loglik + log(sum_p alpha_final[m][p])
    {
        const short* ap = &alpha_lds[g][col * 136 + quad * 8];
        float tot = 0.f;
        #pragma unroll
        for (int kc = 0; kc < 4; ++kc) {
            bf16x8 av = *(const bf16x8*)(ap + kc * 32);
            #pragma unroll
            for (int jj = 0; jj < 8; ++jj) tot += (float)av[jj];
        }
        tot += __shfl_xor(tot, 16);
        tot += __shfl_xor(tot, 32);
        if (quad == 0)
            atomicAdd(out + g * 16 + col, loglik + __logf(tot));
    }
}

extern "C" void kernel_launch(void* const* d_in, const int* in_sizes, int n_in,
                              void* d_out, int out_size, void* d_ws, size_t ws_size,
                              hipStream_t stream) {
    const float* onehot   = (const float*)d_in[0];
    const float* A_logits = (const float*)d_in[1];
    const float* B_logits = (const float*)d_in[2];
    const float* I_logits = (const float*)d_in[3];
    float* ws  = (float*)d_ws;
    float* out = (float*)d_out;
    unsigned char* tok = (unsigned char*)(ws + WS_TOK_F);

    setup_kernel<<<dim3(1024 + NS + 1), dim3(256), 0, stream>>>(
        onehot, A_logits, B_logits, I_logits, ws, out, tok);
    hmm_kernel<<<dim3(NCHUNK), dim3(256), 0, stream>>>(ws, tok, out);
}

// Round 9
// 105.617 us; speedup vs baseline: 1.0805x; 1.0686x over previous
//
#include <hip/hip_runtime.h>
#include <math.h>

#define BATCH 64
#define T 4096
#define ALPH 32
#define NS 128
#define MB 16              // batches per block (MFMA M)
#define NGRP 4             // BATCH/MB
#define NCHUNK 256
#define CL 16              // T/NCHUNK
#define WARM 16

typedef __bf16 bf16x8 __attribute__((ext_vector_type(8)));
typedef short  short8 __attribute__((ext_vector_type(8)));
typedef float  f32x4  __attribute__((ext_vector_type(4)));

// ws layout (float offsets):
//   frag : ushort, 32 frags * 1024 B = 32 KB   at 0      (B-operand fragments of A)
//   Bme  : ushort[32][128] e-major bf16 (8 KB) at 8192   (Bme[tk][c*8+nt] = Bm[tk][nt*16+c])
//   I    : float[128], permuted storage order  at 10240
//   tok  : uchar[BATCH*T]                      at 10368
#define WS_FRAG 0
#define WS_BME  8192
#define WS_I    10240
#define WS_TOK_F 10368

static __device__ inline unsigned short f2u(float f) {
    __bf16 b = (__bf16)f;
    return __builtin_bit_cast(unsigned short, b);
}

// Storage permutation for alpha/I: storage slot p holds logical state
//   n(p) = ((p>>5)*2 + (p&1))*16 + ((p>>1)&15)
// C/D writes pack as dword pairs; A-operand reads are contiguous b128.

// ---------------- setup ----------------
// blocks [0,1024): token extraction; [1024,1152): A-row softmax + frag pack;
// block 1152: Bm column softmax (e-major bf16) + I softmax + zero d_out.
__global__ __launch_bounds__(256) void setup_kernel(const float* __restrict__ onehot,
                                                    const float* __restrict__ A_logits,
                                                    const float* __restrict__ B_logits,
                                                    const float* __restrict__ I_logits,
                                                    float* __restrict__ ws,
                                                    float* __restrict__ out,
                                                    unsigned char* __restrict__ tok) {
    unsigned short* frag = (unsigned short*)(ws + WS_FRAG);
    unsigned short* Bme  = (unsigned short*)(ws + WS_BME);
    float* I_ws = ws + WS_I;
    const int blk = blockIdx.x;
    const int tid = threadIdx.x;

    if (blk < 1024) {
        int b = blk >> 4;
        int t = (blk & 15) * 256 + tid;
        const float4* p = (const float4*)(onehot + ((size_t)b * T + t) * ALPH);
        int tk = 0;
        #pragma unroll
        for (int q = 0; q < 8; ++q) {
            float4 v = p[q];
            if (v.x > 0.5f) tk = 4 * q + 0;
            if (v.y > 0.5f) tk = 4 * q + 1;
            if (v.z > 0.5f) tk = 4 * q + 2;
            if (v.w > 0.5f) tk = 4 * q + 3;
        }
        tok[(size_t)b * T + t] = (unsigned char)tk;
        return;
    }

    if (blk == 1024 + NS) {
        // Bm column softmax -> Bme bf16 e-major; zero out[]
        if (tid < NS) {
            int s = tid;
            float m = -1e30f;
            for (int a = 0; a < ALPH; ++a) m = fmaxf(m, B_logits[a * NS + s]);
            float sum = 0.f;
            for (int a = 0; a < ALPH; ++a) sum += expf(B_logits[a * NS + s] - m);
            float inv = 1.0f / sum;
            int idx = (s & 15) * 8 + (s >> 4);  // c*8 + nt
            for (int a = 0; a < ALPH; ++a)
                Bme[a * NS + idx] = f2u(expf(B_logits[a * NS + s] - m) * inv);
        } else if (tid < NS + BATCH) {
            out[tid - NS] = 0.0f;
        }
        // I softmax
        __shared__ float redm[4];
        __shared__ float reds[4];
        float x = (tid < NS) ? I_logits[tid] : -1e30f;
        float m = x;
        #pragma unroll
        for (int off = 1; off < 64; off <<= 1) m = fmaxf(m, __shfl_xor(m, off));
        int wid = tid >> 6;
        if ((tid & 63) == 0) redm[wid] = m;
        __syncthreads();
        m = fmaxf(fmaxf(redm[0], redm[1]), fmaxf(redm[2], redm[3]));
        float e = (tid < NS) ? expf(x - m) : 0.0f;
        float sg = e;
        #pragma unroll
        for (int off = 1; off < 64; off <<= 1) sg += __shfl_xor(sg, off);
        if ((tid & 63) == 0) reds[wid] = sg;
        __syncthreads();
        float total = (reds[0] + reds[1]) + (reds[2] + reds[3]);
        if (tid < NS) {
            int n = tid;
            int p = (n >> 5) * 32 + (n & 15) * 2 + ((n >> 4) & 1);  // inverse perm
            I_ws[p] = e / total;
        }
        return;
    }

    // A-row softmax, row rho, scattered into MFMA B-fragment layout
    int rho = blk - 1024;
    __shared__ float redm[4];
    __shared__ float reds[4];
    float x = (tid < NS) ? A_logits[rho * NS + tid] : -1e30f;
    float m = x;
    #pragma unroll
    for (int off = 1; off < 64; off <<= 1) m = fmaxf(m, __shfl_xor(m, off));
    int wid = tid >> 6;
    if ((tid & 63) == 0) redm[wid] = m;
    __syncthreads();
    m = fmaxf(fmaxf(redm[0], redm[1]), fmaxf(redm[2], redm[3]));
    float e = (tid < NS) ? expf(x - m) : 0.0f;
    float sg = e;
    #pragma unroll
    for (int off = 1; off < 64; off <<= 1) sg += __shfl_xor(sg, off);
    if ((tid & 63) == 0) reds[wid] = sg;
    __syncthreads();
    float total = (reds[0] + reds[1]) + (reds[2] + reds[3]);
    if (tid < NS) {
        float v = e / total;
        int gamma = tid;
        int kc   = rho >> 5;
        int jlow = (rho >> 4) & 1;
        int quad = (rho >> 2) & 3;
        int j    = (rho & 3) * 2 + jlow;
        int nt   = gamma >> 4;
        int col  = gamma & 15;
        int lane = quad * 16 + col;
        int fid  = kc * 8 + nt;
        frag[fid * 512 + lane * 8 + j] = f2u(v);
    }
}

// ---------------- hmm ----------------
// Block = (batch group g, chunk c), 4 waves SPLIT THE N DIMENSION: wave w
// owns output states [32w, 32w+32) -> 8 MFMAs per wave per step (R4's proven
// 1250-cyc/step shape, with the per-step fat removed: e-major dword emission
// reads, perm-packed dword writes, read-side norm, double-buffered alpha with
// ONE barrier per step). 1024 blocks = 4 blocks/CU.
__global__ __launch_bounds__(256, 4) void hmm_kernel(const float* __restrict__ ws,
                                                     const unsigned char* __restrict__ tok_g,
                                                     float* __restrict__ out) {
    const unsigned short* Bme_g = (const unsigned short*)(ws + WS_BME);
    const float* I_ws = ws + WS_I;
    const unsigned short* frag_g = (const unsigned short*)(ws + WS_FRAG);

    const int g    = blockIdx.x;
    const int c    = blockIdx.y;
    const int tid  = threadIdx.x;
    const int w    = tid >> 6;       // wave -> states [32w, 32w+32) = nt {2w, 2w+1}
    const int lane = tid & 63;
    const int quad = lane >> 4;
    const int col  = lane & 15;

    __shared__ unsigned short Bme_lds[ALPH * NS];                // 8 KB
    __shared__ __align__(16) short alpha_lds[2][MB * 136];       // bf16 double buffer
    __shared__ unsigned char tok_lds[(CL + WARM) * MB];          // [t][m], 512 B

    const int t0u    = c * CL - WARM;
    const int t0     = (t0u < 0) ? 0 : t0u;
    const bool exact = (t0 == 0);
    const int nsteps = (c + 1) * CL - 1 - t0;
    const int ntok   = nsteps + 1;
    const int resetj = c * CL - t0;   // 0 for exact c==0 (never fires); 16 for c==1

    // stage Bme (coalesced dwords)
    {
        const unsigned* src = (const unsigned*)Bme_g;
        unsigned* dst = (unsigned*)Bme_lds;
        #pragma unroll
        for (int i = 0; i < 8; ++i) dst[i * 256 + tid] = src[i * 256 + tid];
    }
    // stage tokens [t][m] for this group's 16 batches
    for (int i = tid; i < ntok * MB; i += 256)
        tok_lds[i] = tok_g[(size_t)(g * MB + (i & 15)) * T + t0 + (i >> 4)];

    // B-fragments for this wave's nt pair: bfr[kc][b], 32 VGPRs total
    bf16x8 bfr[4][2];
    #pragma unroll
    for (int kc = 0; kc < 4; ++kc)
        #pragma unroll
        for (int b = 0; b < 2; ++b)
            bfr[kc][b] = __builtin_bit_cast(bf16x8,
                *(const short8*)(frag_g + (size_t)(kc * 8 + 2 * w + b) * 512 + lane * 8));

    __syncthreads();

    // initial alpha in storage order: exact chunks I*E0, else uniform
    #pragma unroll
    for (int it = 0; it < 8; ++it) {
        int idx = it * 256 + tid;
        int m = idx >> 7, p = idx & 127;
        float val;
        if (exact) {
            int tk0 = tok_lds[m];
            int nt = ((p >> 5) << 1) + (p & 1);
            int cc = (p >> 1) & 15;
            float bm = (float)__builtin_bit_cast(__bf16, Bme_lds[tk0 * NS + cc * 8 + nt]);
            val = I_ws[p] * bm;
        } else {
            val = 1.0f;
        }
        alpha_lds[0][m * 136 + p] = (short)f2u(val);
    }
    __syncthreads();

    float loglik = 0.0f;  // ledger for batch m=col (uniform across quads/waves)

    for (int j = 1; j <= nsteps; ++j) {
        const int rb = (j + 1) & 1;
        const int wb = j & 1;
        const bool do_norm = ((j & 7) == 0);   // includes j==16==resetj

        // emission dwords (independent of alpha): states (2w)*16+col, (2w+1)*16+col
        unsigned tokp = *(const unsigned*)&tok_lds[j * MB + quad * 4];
        unsigned eu[4];
        #pragma unroll
        for (int r = 0; r < 4; ++r) {
            int tk = (tokp >> (8 * r)) & 255;
            eu[r] = *(const unsigned*)&Bme_lds[tk * NS + col * 8 + 2 * w];
        }

        // A-operand fragments (full K for batch m=col)
        const short* ap = &alpha_lds[rb][col * 136 + quad * 8];
        bf16x8 afr[4];
        #pragma unroll
        for (int kc = 0; kc < 4; ++kc)
            afr[kc] = *(const bf16x8*)(ap + kc * 32);

        f32x4 acc0 = {0.f, 0.f, 0.f, 0.f};
        f32x4 acc1 = {0.f, 0.f, 0.f, 0.f};
        #pragma unroll
        for (int kc = 0; kc < 4; ++kc) {
            acc0 = __builtin_amdgcn_mfma_f32_16x16x32_bf16(afr[kc], bfr[kc][0], acc0, 0, 0, 0);
            acc1 = __builtin_amdgcn_mfma_f32_16x16x32_bf16(afr[kc], bfr[kc][1], acc1, 0, 0, 0);
        }

        float v0[4], v1[4];
        #pragma unroll
        for (int r = 0; r < 4; ++r) {
            float e0 = __builtin_bit_cast(float, eu[r] << 16);
            float e1 = __builtin_bit_cast(float, eu[r] & 0xffff0000u);
            v0[r] = acc0[r] * e0;
            v1[r] = acc1[r] * e1;
        }

        if (do_norm) {
            float asum = 0.f;
            #pragma unroll
            for (int kc = 0; kc < 4; ++kc)
                #pragma unroll
                for (int jj = 0; jj < 8; ++jj) asum += (float)afr[kc][jj];
            asum += __shfl_xor(asum, 16);
            asum += __shfl_xor(asum, 32);       // full mass of batch m=col
            float lg = __logf(asum);
            loglik = (j == resetj) ? 0.0f : (loglik + lg);
            #pragma unroll
            for (int r = 0; r < 4; ++r) {
                float iv = __builtin_amdgcn_rcpf(__shfl(asum, quad * 4 + r));
                v0[r] *= iv;
                v1[r] *= iv;
            }
        }

        // pack (round-half-up, alpha>0) + ONE dword write per r (storage order:
        // states (2w,2w+1)*16+col land at adjacent slots p = w*32 + col*2 + {0,1})
        #pragma unroll
        for (int r = 0; r < 4; ++r) {
            unsigned u0 = __builtin_bit_cast(unsigned, v0[r]) + 0x8000u;
            unsigned u1 = __builtin_bit_cast(unsigned, v1[r]) + 0x8000u;
            unsigned dw = __builtin_amdgcn_perm(u1, u0, 0x07060302u);
            ((unsigned*)&alpha_lds[wb][0])[(quad * 4 + r) * 68 + w * 16 + col] = dw;
        }
        __syncthreads();
    }

    // final flush: out[m] += loglik + log(sum_p alpha_final[m][p])
    {
        const short* ap = &alpha_lds[nsteps & 1][col * 136 + quad * 8];
        float tot = 0.f;
        #pragma unroll
        for (int kc = 0; kc < 4; ++kc) {
            bf16x8 av = *(const bf16x8*)(ap + kc * 32);
            #pragma unroll
            for (int jj = 0; jj < 8; ++jj) tot += (float)av[jj];
        }
        tot += __shfl_xor(tot, 16);
        tot += __shfl_xor(tot, 32);
        if (w == 0 && quad == 0)
            atomicAdd(out + g * MB + col, loglik + __logf(tot));
    }
}

extern "C" void kernel_launch(void* const* d_in, const int* in_sizes, int n_in,
                              void* d_out, int out_size, void* d_ws, size_t ws_size,
                              hipStream_t stream) {
    const float* onehot   = (const float*)d_in[0];
    const float* A_logits = (const float*)d_in[1];
    const float* B_logits = (const float*)d_in[2];
    const float* I_logits = (const float*)d_in[3];
    float* ws  = (float*)d_ws;
    float* out = (float*)d_out;
    unsigned char* tok = (unsigned char*)(ws + WS_TOK_F);

    setup_kernel<<<dim3(1024 + NS + 1), dim3(256), 0, stream>>>(
        onehot, A_logits, B_logits, I_logits, ws, out, tok);
    hmm_kernel<<<dim3(NGRP, NCHUNK), dim3(256), 0, stream>>>(ws, tok, out);
}

// Round 10
// 102.165 us; speedup vs baseline: 1.1170x; 1.0338x over previous
//
#include <hip/hip_runtime.h>
#include <math.h>

#define BATCH 64
#define T 4096
#define ALPH 32
#define NS 128
#define MB 16              // batches per block (MFMA M)
#define NGRP 4             // BATCH/MB
#define NCHUNK 256
#define CL 16              // T/NCHUNK
#define WARM 8
#define NTOKF (CL + WARM)  // 24 — fixed fetch count, valid for every chunk

typedef __bf16 bf16x8 __attribute__((ext_vector_type(8)));
typedef short  short8 __attribute__((ext_vector_type(8)));
typedef float  f32x4  __attribute__((ext_vector_type(4)));

// ws layout (float offsets):
//   frag : ushort, 32 frags * 1024 B = 32 KB   at 0      (B-operand fragments of A)
//   Bme  : ushort[32][128] e-major bf16 (8 KB) at 8192   (Bme[tk][c*8+nt] = Bm[tk][nt*16+c])
//   I    : float[128], permuted storage order  at 10240
#define WS_FRAG 0
#define WS_BME  8192
#define WS_I    10240

static __device__ inline unsigned short f2u(float f) {
    __bf16 b = (__bf16)f;
    return __builtin_bit_cast(unsigned short, b);
}

// Storage permutation for alpha/I: storage slot p holds logical state
//   n(p) = ((p>>5)*2 + (p&1))*16 + ((p>>1)&15)
// C/D writes pack as dword pairs; A-operand reads are contiguous b128.

// ---------------- prep ----------------
// blocks [0,128): A-row softmax + frag pack; block 128: Bm column softmax
// (e-major bf16) + I softmax + zero d_out.
__global__ __launch_bounds__(256) void prep_kernel(const float* __restrict__ A_logits,
                                                   const float* __restrict__ B_logits,
                                                   const float* __restrict__ I_logits,
                                                   float* __restrict__ ws,
                                                   float* __restrict__ out) {
    unsigned short* frag = (unsigned short*)(ws + WS_FRAG);
    unsigned short* Bme  = (unsigned short*)(ws + WS_BME);
    float* I_ws = ws + WS_I;
    const int blk = blockIdx.x;
    const int tid = threadIdx.x;

    if (blk == NS) {
        // Bm column softmax -> Bme bf16 e-major; zero out[]
        if (tid < NS) {
            int s = tid;
            float m = -1e30f;
            for (int a = 0; a < ALPH; ++a) m = fmaxf(m, B_logits[a * NS + s]);
            float sum = 0.f;
            for (int a = 0; a < ALPH; ++a) sum += expf(B_logits[a * NS + s] - m);
            float inv = 1.0f / sum;
            int idx = (s & 15) * 8 + (s >> 4);  // c*8 + nt
            for (int a = 0; a < ALPH; ++a)
                Bme[a * NS + idx] = f2u(expf(B_logits[a * NS + s] - m) * inv);
        } else if (tid < NS + BATCH) {
            out[tid - NS] = 0.0f;
        }
        // I softmax
        __shared__ float redm[4];
        __shared__ float reds[4];
        float x = (tid < NS) ? I_logits[tid] : -1e30f;
        float m = x;
        #pragma unroll
        for (int off = 1; off < 64; off <<= 1) m = fmaxf(m, __shfl_xor(m, off));
        int wid = tid >> 6;
        if ((tid & 63) == 0) redm[wid] = m;
        __syncthreads();
        m = fmaxf(fmaxf(redm[0], redm[1]), fmaxf(redm[2], redm[3]));
        float e = (tid < NS) ? expf(x - m) : 0.0f;
        float sg = e;
        #pragma unroll
        for (int off = 1; off < 64; off <<= 1) sg += __shfl_xor(sg, off);
        if ((tid & 63) == 0) reds[wid] = sg;
        __syncthreads();
        float total = (reds[0] + reds[1]) + (reds[2] + reds[3]);
        if (tid < NS) {
            int n = tid;
            int p = (n >> 5) * 32 + (n & 15) * 2 + ((n >> 4) & 1);  // inverse perm
            I_ws[p] = e / total;
        }
        return;
    }

    // A-row softmax, row rho, scattered into MFMA B-fragment layout
    int rho = blk;
    __shared__ float redm[4];
    __shared__ float reds[4];
    float x = (tid < NS) ? A_logits[rho * NS + tid] : -1e30f;
    float m = x;
    #pragma unroll
    for (int off = 1; off < 64; off <<= 1) m = fmaxf(m, __shfl_xor(m, off));
    int wid = tid >> 6;
    if ((tid & 63) == 0) redm[wid] = m;
    __syncthreads();
    m = fmaxf(fmaxf(redm[0], redm[1]), fmaxf(redm[2], redm[3]));
    float e = (tid < NS) ? expf(x - m) : 0.0f;
    float sg = e;
    #pragma unroll
    for (int off = 1; off < 64; off <<= 1) sg += __shfl_xor(sg, off);
    if ((tid & 63) == 0) reds[wid] = sg;
    __syncthreads();
    float total = (reds[0] + reds[1]) + (reds[2] + reds[3]);
    if (tid < NS) {
        float v = e / total;
        int gamma = tid;
        int kc   = rho >> 5;
        int jlow = (rho >> 4) & 1;
        int quad = (rho >> 2) & 3;
        int j    = (rho & 3) * 2 + jlow;
        int nt   = gamma >> 4;
        int col  = gamma & 15;
        int lane = quad * 16 + col;
        int fid  = kc * 8 + nt;
        frag[fid * 512 + lane * 8 + j] = f2u(v);
    }
}

// ---------------- hmm ----------------
// Block = (batch group g, chunk c), 4 waves split the N dimension: wave w
// owns output states [32w, 32w+32) -> 8 MFMAs per wave per step, one barrier
// per step, double-buffered bf16 alpha, read-side normalization. Token
// extraction fused: each block fetches its own 16x24 one-hot rows (L3-backed).
// WARM=8: chain length 23; resetj=8 coincides with the norm cadence (j&7==0).
__global__ __launch_bounds__(256, 4) void hmm_kernel(const float* __restrict__ onehot,
                                                     const float* __restrict__ ws,
                                                     float* __restrict__ out) {
    const unsigned short* Bme_g = (const unsigned short*)(ws + WS_BME);
    const float* I_ws = ws + WS_I;
    const unsigned short* frag_g = (const unsigned short*)(ws + WS_FRAG);

    const int g    = blockIdx.x;
    const int c    = blockIdx.y;
    const int tid  = threadIdx.x;
    const int w    = tid >> 6;       // wave -> states [32w, 32w+32) = nt {2w, 2w+1}
    const int lane = tid & 63;
    const int quad = lane >> 4;
    const int col  = lane & 15;

    __shared__ unsigned short Bme_lds[ALPH * NS];                // 8 KB
    __shared__ __align__(16) short alpha_lds[2][MB * 136];       // bf16 double buffer
    __shared__ unsigned char tok_lds[NTOKF * MB];                // [t][m], 384 B

    const int t0u    = c * CL - WARM;
    const int t0     = (t0u < 0) ? 0 : t0u;
    const bool exact = (t0 == 0);
    const int nsteps = (c + 1) * CL - 1 - t0;   // 15 for c==0, else 23
    const int resetj = c * CL - t0;             // 0 for c==0 (never fires); 8 else

    // fused token extraction: fixed 24 t-values (c=255 ends exactly at t=4095).
    // t-inner worker id -> 24 consecutive 128B rows per batch (L3-coalesced).
    for (int id = tid; id < NTOKF * MB; id += 256) {
        int t = id % NTOKF;
        int m = id / NTOKF;
        const float4* p = (const float4*)(onehot + ((size_t)(g * MB + m) * T + t0 + t) * ALPH);
        int tk = 0;
        #pragma unroll
        for (int q = 0; q < 8; ++q) {
            float4 v = p[q];
            if (v.x > 0.5f) tk = 4 * q + 0;
            if (v.y > 0.5f) tk = 4 * q + 1;
            if (v.z > 0.5f) tk = 4 * q + 2;
            if (v.w > 0.5f) tk = 4 * q + 3;
        }
        tok_lds[t * MB + m] = (unsigned char)tk;
    }

    // stage Bme (coalesced dwords)
    {
        const unsigned* src = (const unsigned*)Bme_g;
        unsigned* dst = (unsigned*)Bme_lds;
        #pragma unroll
        for (int i = 0; i < 8; ++i) dst[i * 256 + tid] = src[i * 256 + tid];
    }

    // B-fragments for this wave's nt pair: bfr[kc][b], 32 VGPRs total
    bf16x8 bfr[4][2];
    #pragma unroll
    for (int kc = 0; kc < 4; ++kc)
        #pragma unroll
        for (int b = 0; b < 2; ++b)
            bfr[kc][b] = __builtin_bit_cast(bf16x8,
                *(const short8*)(frag_g + (size_t)(kc * 8 + 2 * w + b) * 512 + lane * 8));

    __syncthreads();

    // initial alpha in storage order: exact chunk I*E0, else uniform
    #pragma unroll
    for (int it = 0; it < 8; ++it) {
        int idx = it * 256 + tid;
        int m = idx >> 7, p = idx & 127;
        float val;
        if (exact) {
            int tk0 = tok_lds[m];
            int nt = ((p >> 5) << 1) + (p & 1);
            int cc = (p >> 1) & 15;
            float bm = (float)__builtin_bit_cast(__bf16, Bme_lds[tk0 * NS + cc * 8 + nt]);
            val = I_ws[p] * bm;
        } else {
            val = 1.0f;
        }
        alpha_lds[0][m * 136 + p] = (short)f2u(val);
    }
    __syncthreads();

    float loglik = 0.0f;  // ledger for batch m=col (uniform across quads/waves)

    for (int j = 1; j <= nsteps; ++j) {
        const int rb = (j + 1) & 1;
        const int wb = j & 1;
        const bool do_norm = ((j & 7) == 0);   // includes j==8==resetj

        // emission dwords (independent of alpha): states (2w)*16+col, (2w+1)*16+col
        unsigned tokp = *(const unsigned*)&tok_lds[j * MB + quad * 4];
        unsigned eu[4];
        #pragma unroll
        for (int r = 0; r < 4; ++r) {
            int tk = (tokp >> (8 * r)) & 255;
            eu[r] = *(const unsigned*)&Bme_lds[tk * NS + col * 8 + 2 * w];
        }

        // A-operand fragments (full K for batch m=col)
        const short* ap = &alpha_lds[rb][col * 136 + quad * 8];
        bf16x8 afr[4];
        #pragma unroll
        for (int kc = 0; kc < 4; ++kc)
            afr[kc] = *(const bf16x8*)(ap + kc * 32);

        f32x4 acc0 = {0.f, 0.f, 0.f, 0.f};
        f32x4 acc1 = {0.f, 0.f, 0.f, 0.f};
        #pragma unroll
        for (int kc = 0; kc < 4; ++kc) {
            acc0 = __builtin_amdgcn_mfma_f32_16x16x32_bf16(afr[kc], bfr[kc][0], acc0, 0, 0, 0);
            acc1 = __builtin_amdgcn_mfma_f32_16x16x32_bf16(afr[kc], bfr[kc][1], acc1, 0, 0, 0);
        }

        float v0[4], v1[4];
        #pragma unroll
        for (int r = 0; r < 4; ++r) {
            float e0 = __builtin_bit_cast(float, eu[r] << 16);
            float e1 = __builtin_bit_cast(float, eu[r] & 0xffff0000u);
            v0[r] = acc0[r] * e0;
            v1[r] = acc1[r] * e1;
        }

        if (do_norm) {
            float asum = 0.f;
            #pragma unroll
            for (int kc = 0; kc < 4; ++kc)
                #pragma unroll
                for (int jj = 0; jj < 8; ++jj) asum += (float)afr[kc][jj];
            asum += __shfl_xor(asum, 16);
            asum += __shfl_xor(asum, 32);       // full mass of batch m=col
            float lg = __logf(asum);
            loglik = (j == resetj) ? 0.0f : (loglik + lg);
            #pragma unroll
            for (int r = 0; r < 4; ++r) {
                float iv = __builtin_amdgcn_rcpf(__shfl(asum, quad * 4 + r));
                v0[r] *= iv;
                v1[r] *= iv;
            }
        }

        // pack (round-half-up, alpha>0) + ONE dword write per r (storage order:
        // states (2w,2w+1)*16+col land at adjacent slots p = w*32 + col*2 + {0,1})
        #pragma unroll
        for (int r = 0; r < 4; ++r) {
            unsigned u0 = __builtin_bit_cast(unsigned, v0[r]) + 0x8000u;
            unsigned u1 = __builtin_bit_cast(unsigned, v1[r]) + 0x8000u;
            unsigned dw = __builtin_amdgcn_perm(u1, u0, 0x07060302u);
            ((unsigned*)&alpha_lds[wb][0])[(quad * 4 + r) * 68 + w * 16 + col] = dw;
        }
        __syncthreads();
    }

    // final flush: out[m] += loglik + log(sum_p alpha_final[m][p])
    {
        const short* ap = &alpha_lds[nsteps & 1][col * 136 + quad * 8];
        float tot = 0.f;
        #pragma unroll
        for (int kc = 0; kc < 4; ++kc) {
            bf16x8 av = *(const bf16x8*)(ap + kc * 32);
            #pragma unroll
            for (int jj = 0; jj < 8; ++jj) tot += (float)av[jj];
        }
        tot += __shfl_xor(tot, 16);
        tot += __shfl_xor(tot, 32);
        if (w == 0 && quad == 0)
            atomicAdd(out + g * MB + col, loglik + __logf(tot));
    }
}

extern "C" void kernel_launch(void* const* d_in, const int* in_sizes, int n_in,
                              void* d_out, int out_size, void* d_ws, size_t ws_size,
                              hipStream_t stream) {
    const float* onehot   = (const float*)d_in[0];
    const float* A_logits = (const float*)d_in[1];
    const float* B_logits = (const float*)d_in[2];
    const float* I_logits = (const float*)d_in[3];
    float* ws  = (float*)d_ws;
    float* out = (float*)d_out;

    prep_kernel<<<dim3(NS + 1), dim3(256), 0, stream>>>(A_logits, B_logits, I_logits, ws, out);
    hmm_kernel<<<dim3(NGRP, NCHUNK), dim3(256), 0, stream>>>(onehot, ws, out);
}

// Round 11
// 99.180 us; speedup vs baseline: 1.1506x; 1.0301x over previous
//
#include <hip/hip_runtime.h>
#include <math.h>

#define BATCH 64
#define T 4096
#define ALPH 32
#define NS 128
#define MB 16              // batches per block (MFMA M)
#define NGRP 4             // BATCH/MB
#define NCHUNK 256
#define CL 16              // T/NCHUNK
#define WARM 4
#define NTOKF (CL + WARM)  // 20 — fixed fetch count, valid for every chunk

typedef __bf16 bf16x8 __attribute__((ext_vector_type(8)));
typedef short  short8 __attribute__((ext_vector_type(8)));
typedef float  f32x4  __attribute__((ext_vector_type(4)));

// ws layout (float offsets):
//   frag : ushort, 32 frags * 1024 B = 32 KB   at 0      (B-operand fragments of A)
//   Bme  : ushort[32][128] e-major bf16 (8 KB) at 8192   (Bme[tk][c*8+nt] = Bm[tk][nt*16+c])
//   I    : float[128], permuted storage order  at 10240
//   tok  : uchar[BATCH*T] (256 KB)             at 10368
#define WS_FRAG 0
#define WS_BME  8192
#define WS_I    10240
#define WS_TOK_F 10368

static __device__ inline unsigned short f2u(float f) {
    __bf16 b = (__bf16)f;
    return __builtin_bit_cast(unsigned short, b);
}

// Storage permutation for alpha/I: storage slot p holds logical state
//   n(p) = ((p>>5)*2 + (p&1))*16 + ((p>>1)&15)
// C/D writes pack as dword pairs; A-operand reads are contiguous b128.

// ---------------- prep ----------------
// blocks [0,1024): token extraction (one coalesced 33.5 MB pass);
// blocks [1024,1152): A-row softmax + frag pack;
// block 1152: Bm column softmax (e-major bf16) + I softmax + zero d_out.
__global__ __launch_bounds__(256) void prep_kernel(const float* __restrict__ onehot,
                                                   const float* __restrict__ A_logits,
                                                   const float* __restrict__ B_logits,
                                                   const float* __restrict__ I_logits,
                                                   float* __restrict__ ws,
                                                   float* __restrict__ out,
                                                   unsigned char* __restrict__ tok) {
    unsigned short* frag = (unsigned short*)(ws + WS_FRAG);
    unsigned short* Bme  = (unsigned short*)(ws + WS_BME);
    float* I_ws = ws + WS_I;
    const int blk = blockIdx.x;
    const int tid = threadIdx.x;

    if (blk < 1024) {
        int b = blk >> 4;
        int t = (blk & 15) * 256 + tid;
        const float4* p = (const float4*)(onehot + ((size_t)b * T + t) * ALPH);
        int tk = 0;
        #pragma unroll
        for (int q = 0; q < 8; ++q) {
            float4 v = p[q];
            if (v.x > 0.5f) tk = 4 * q + 0;
            if (v.y > 0.5f) tk = 4 * q + 1;
            if (v.z > 0.5f) tk = 4 * q + 2;
            if (v.w > 0.5f) tk = 4 * q + 3;
        }
        tok[(size_t)b * T + t] = (unsigned char)tk;
        return;
    }

    if (blk == 1024 + NS) {
        // Bm column softmax -> Bme bf16 e-major; zero out[]
        if (tid < NS) {
            int s = tid;
            float m = -1e30f;
            for (int a = 0; a < ALPH; ++a) m = fmaxf(m, B_logits[a * NS + s]);
            float sum = 0.f;
            for (int a = 0; a < ALPH; ++a) sum += expf(B_logits[a * NS + s] - m);
            float inv = 1.0f / sum;
            int idx = (s & 15) * 8 + (s >> 4);  // c*8 + nt
            for (int a = 0; a < ALPH; ++a)
                Bme[a * NS + idx] = f2u(expf(B_logits[a * NS + s] - m) * inv);
        } else if (tid < NS + BATCH) {
            out[tid - NS] = 0.0f;
        }
        // I softmax
        __shared__ float redm[4];
        __shared__ float reds[4];
        float x = (tid < NS) ? I_logits[tid] : -1e30f;
        float m = x;
        #pragma unroll
        for (int off = 1; off < 64; off <<= 1) m = fmaxf(m, __shfl_xor(m, off));
        int wid = tid >> 6;
        if ((tid & 63) == 0) redm[wid] = m;
        __syncthreads();
        m = fmaxf(fmaxf(redm[0], redm[1]), fmaxf(redm[2], redm[3]));
        float e = (tid < NS) ? expf(x - m) : 0.0f;
        float sg = e;
        #pragma unroll
        for (int off = 1; off < 64; off <<= 1) sg += __shfl_xor(sg, off);
        if ((tid & 63) == 0) reds[wid] = sg;
        __syncthreads();
        float total = (reds[0] + reds[1]) + (reds[2] + reds[3]);
        if (tid < NS) {
            int n = tid;
            int p = (n >> 5) * 32 + (n & 15) * 2 + ((n >> 4) & 1);  // inverse perm
            I_ws[p] = e / total;
        }
        return;
    }

    // A-row softmax, row rho, scattered into MFMA B-fragment layout
    int rho = blk - 1024;
    __shared__ float redm[4];
    __shared__ float reds[4];
    float x = (tid < NS) ? A_logits[rho * NS + tid] : -1e30f;
    float m = x;
    #pragma unroll
    for (int off = 1; off < 64; off <<= 1) m = fmaxf(m, __shfl_xor(m, off));
    int wid = tid >> 6;
    if ((tid & 63) == 0) redm[wid] = m;
    __syncthreads();
    m = fmaxf(fmaxf(redm[0], redm[1]), fmaxf(redm[2], redm[3]));
    float e = (tid < NS) ? expf(x - m) : 0.0f;
    float sg = e;
    #pragma unroll
    for (int off = 1; off < 64; off <<= 1) sg += __shfl_xor(sg, off);
    if ((tid & 63) == 0) reds[wid] = sg;
    __syncthreads();
    float total = (reds[0] + reds[1]) + (reds[2] + reds[3]);
    if (tid < NS) {
        float v = e / total;
        int gamma = tid;
        int kc   = rho >> 5;
        int jlow = (rho >> 4) & 1;
        int quad = (rho >> 2) & 3;
        int j    = (rho & 3) * 2 + jlow;
        int nt   = gamma >> 4;
        int col  = gamma & 15;
        int lane = quad * 16 + col;
        int fid  = kc * 8 + nt;
        frag[fid * 512 + lane * 8 + j] = f2u(v);
    }
}

// ---------------- hmm ----------------
// Block = (batch group g, chunk c), 4 waves split the N dimension: wave w
// owns output states [32w, 32w+32), 8 MFMAs per wave per step, one barrier
// per step, double-buffered bf16 alpha, read-side normalization. Tokens come
// precomputed from prep (320 B/block). WARM=4: chain 19 (15 for c==0);
// ledger discard fires at j==resetj==4 (added to the norm cadence).
__global__ __launch_bounds__(256, 4) void hmm_kernel(const float* __restrict__ ws,
                                                     const unsigned char* __restrict__ tok_g,
                                                     float* __restrict__ out) {
    const unsigned short* Bme_g = (const unsigned short*)(ws + WS_BME);
    const float* I_ws = ws + WS_I;
    const unsigned short* frag_g = (const unsigned short*)(ws + WS_FRAG);

    const int g    = blockIdx.x;
    const int c    = blockIdx.y;
    const int tid  = threadIdx.x;
    const int w    = tid >> 6;       // wave -> states [32w, 32w+32) = nt {2w, 2w+1}
    const int lane = tid & 63;
    const int quad = lane >> 4;
    const int col  = lane & 15;

    __shared__ unsigned short Bme_lds[ALPH * NS];                // 8 KB
    __shared__ __align__(16) short alpha_lds[2][MB * 136];       // bf16 double buffer
    __shared__ unsigned char tok_lds[NTOKF * MB];                // [t][m], 320 B

    const int t0u    = c * CL - WARM;
    const int t0     = (t0u < 0) ? 0 : t0u;
    const bool exact = (t0 == 0);
    const int nsteps = (c + 1) * CL - 1 - t0;   // 15 for c==0, else 19
    const int resetj = c * CL - t0;             // 0 for c==0 (never fires); 4 else

    // stage tokens [t][m] (tiny: 320 B)
    for (int i = tid; i < NTOKF * MB; i += 256)
        tok_lds[i] = tok_g[(size_t)(g * MB + (i & 15)) * T + t0 + (i >> 4)];

    // stage Bme (coalesced dwords)
    {
        const unsigned* src = (const unsigned*)Bme_g;
        unsigned* dst = (unsigned*)Bme_lds;
        #pragma unroll
        for (int i = 0; i < 8; ++i) dst[i * 256 + tid] = src[i * 256 + tid];
    }

    // B-fragments for this wave's nt pair: bfr[kc][b], 32 VGPRs total
    bf16x8 bfr[4][2];
    #pragma unroll
    for (int kc = 0; kc < 4; ++kc)
        #pragma unroll
        for (int b = 0; b < 2; ++b)
            bfr[kc][b] = __builtin_bit_cast(bf16x8,
                *(const short8*)(frag_g + (size_t)(kc * 8 + 2 * w + b) * 512 + lane * 8));

    __syncthreads();

    // initial alpha in storage order: exact chunk I*E0, else uniform
    #pragma unroll
    for (int it = 0; it < 8; ++it) {
        int idx = it * 256 + tid;
        int m = idx >> 7, p = idx & 127;
        float val;
        if (exact) {
            int tk0 = tok_lds[m];
            int nt = ((p >> 5) << 1) + (p & 1);
            int cc = (p >> 1) & 15;
            float bm = (float)__builtin_bit_cast(__bf16, Bme_lds[tk0 * NS + cc * 8 + nt]);
            val = I_ws[p] * bm;
        } else {
            val = 1.0f;
        }
        alpha_lds[0][m * 136 + p] = (short)f2u(val);
    }
    __syncthreads();

    float loglik = 0.0f;  // ledger for batch m=col (uniform across quads/waves)

    for (int j = 1; j <= nsteps; ++j) {
        const int rb = (j + 1) & 1;
        const int wb = j & 1;
        const bool do_norm = ((j & 7) == 0) || (j == resetj);

        // emission dwords (independent of alpha): states (2w)*16+col, (2w+1)*16+col
        unsigned tokp = *(const unsigned*)&tok_lds[j * MB + quad * 4];
        unsigned eu[4];
        #pragma unroll
        for (int r = 0; r < 4; ++r) {
            int tk = (tokp >> (8 * r)) & 255;
            eu[r] = *(const unsigned*)&Bme_lds[tk * NS + col * 8 + 2 * w];
        }

        // A-operand fragments (full K for batch m=col)
        const short* ap = &alpha_lds[rb][col * 136 + quad * 8];
        bf16x8 afr[4];
        #pragma unroll
        for (int kc = 0; kc < 4; ++kc)
            afr[kc] = *(const bf16x8*)(ap + kc * 32);

        f32x4 acc0 = {0.f, 0.f, 0.f, 0.f};
        f32x4 acc1 = {0.f, 0.f, 0.f, 0.f};
        #pragma unroll
        for (int kc = 0; kc < 4; ++kc) {
            acc0 = __builtin_amdgcn_mfma_f32_16x16x32_bf16(afr[kc], bfr[kc][0], acc0, 0, 0, 0);
            acc1 = __builtin_amdgcn_mfma_f32_16x16x32_bf16(afr[kc], bfr[kc][1], acc1, 0, 0, 0);
        }

        float v0[4], v1[4];
        #pragma unroll
        for (int r = 0; r < 4; ++r) {
            float e0 = __builtin_bit_cast(float, eu[r] << 16);
            float e1 = __builtin_bit_cast(float, eu[r] & 0xffff0000u);
            v0[r] = acc0[r] * e0;
            v1[r] = acc1[r] * e1;
        }

        if (do_norm) {
            float asum = 0.f;
            #pragma unroll
            for (int kc = 0; kc < 4; ++kc)
                #pragma unroll
                for (int jj = 0; jj < 8; ++jj) asum += (float)afr[kc][jj];
            asum += __shfl_xor(asum, 16);
            asum += __shfl_xor(asum, 32);       // full mass of batch m=col
            float lg = __logf(asum);
            loglik = (j == resetj) ? 0.0f : (loglik + lg);
            #pragma unroll
            for (int r = 0; r < 4; ++r) {
                float iv = __builtin_amdgcn_rcpf(__shfl(asum, quad * 4 + r));
                v0[r] *= iv;
                v1[r] *= iv;
            }
        }

        // pack (round-half-up, alpha>0) + ONE dword write per r (storage order:
        // states (2w,2w+1)*16+col land at adjacent slots p = w*32 + col*2 + {0,1})
        #pragma unroll
        for (int r = 0; r < 4; ++r) {
            unsigned u0 = __builtin_bit_cast(unsigned, v0[r]) + 0x8000u;
            unsigned u1 = __builtin_bit_cast(unsigned, v1[r]) + 0x8000u;
            unsigned dw = __builtin_amdgcn_perm(u1, u0, 0x07060302u);
            ((unsigned*)&alpha_lds[wb][0])[(quad * 4 + r) * 68 + w * 16 + col] = dw;
        }
        __syncthreads();
    }

    // final flush: out[m] += loglik + log(sum_p alpha_final[m][p])
    {
        const short* ap = &alpha_lds[nsteps & 1][col * 136 + quad * 8];
        float tot = 0.f;
        #pragma unroll
        for (int kc = 0; kc < 4; ++kc) {
            bf16x8 av = *(const bf16x8*)(ap + kc * 32);
            #pragma unroll
            for (int jj = 0; jj < 8; ++jj) tot += (float)av[jj];
        }
        tot += __shfl_xor(tot, 16);
        tot += __shfl_xor(tot, 32);
        if (w == 0 && quad == 0)
            atomicAdd(out + g * MB + col, loglik + __logf(tot));
    }
}

extern "C" void kernel_launch(void* const* d_in, const int* in_sizes, int n_in,
                              void* d_out, int out_size, void* d_ws, size_t ws_size,
                              hipStream_t stream) {
    const float* onehot   = (const float*)d_in[0];
    const float* A_logits = (const float*)d_in[1];
    const float* B_logits = (const float*)d_in[2];
    const float* I_logits = (const float*)d_in[3];
    float* ws  = (float*)d_ws;
    float* out = (float*)d_out;
    unsigned char* tok = (unsigned char*)(ws + WS_TOK_F);

    prep_kernel<<<dim3(1024 + NS + 1), dim3(256), 0, stream>>>(
        onehot, A_logits, B_logits, I_logits, ws, out, tok);
    hmm_kernel<<<dim3(NGRP, NCHUNK), dim3(256), 0, stream>>>(ws, tok, out);
}